// Round 3
// baseline (319.307 us; speedup 1.0000x reference)
//
#include <hip/hip_runtime.h>
#include <math.h>

#define BB 2048
#define TT 200
#define CC 128
#define PADV (-4294967295.0f)
#define SCALE 0.08838834764831845f   // 1/sqrt(128)
#define INVT (1.0f / 200.0f)

// One block per batch row. 256 threads = 4 waves. ~5 KB LDS.
// __launch_bounds__(256,8): 8 waves/SIMD -> 8 blocks/CU -> 2048 blocks in ONE round.
// keys read twice from global; second read served by L2/L3 (per-block set = 100 KB).
__global__ __launch_bounds__(256, 8) void user_attn_kernel(
    const float* __restrict__ uq,    // [B,1,C]
    const float* __restrict__ keys,  // [B,T,C]
    const int*   __restrict__ klen,  // [B,1]
    const float* __restrict__ W,     // [C,C] row-major W[c][d]
    const float* __restrict__ bias,  // [C]
    float*       __restrict__ out)   // [B,1,C]
{
    const int b    = blockIdx.x;
    const int tid  = threadIdx.x;
    const int lane = tid & 63;
    const int wid  = tid >> 6;       // 0..3
    const int cl   = lane & 31;      // channel-group lane
    const int h    = lane >> 5;      // half-wave -> row parity
    const int c4   = cl * 4;

    __shared__ float  s_q[CC];
    __shared__ float  s_uq[CC];
    __shared__ float  s_part[2 * CC];
    __shared__ float  s_w[TT];
    __shared__ float  s_tmp[8];
    __shared__ float4 s_red[4 * 32];

    const float* kb = keys + (size_t)b * TT * CC;

    // ---- phase 0: q = tanh(uq @ W + bias); 256 threads, 2 partials per channel
    if (tid < CC) s_uq[tid] = uq[b * CC + tid];
    __syncthreads();
    {
        const int d    = tid & 127;
        const int part = tid >> 7;        // 0 or 1
        const int c0   = part * 64;
        float acc = 0.0f;
        #pragma unroll 16
        for (int c = 0; c < 64; ++c)
            acc = fmaf(s_uq[c0 + c], W[(c0 + c) * CC + d], acc);
        s_part[part * CC + d] = acc;
    }
    __syncthreads();
    if (tid < CC)
        s_q[tid] = tanhf(bias[tid] + s_part[tid] + s_part[CC + tid]);
    __syncthreads();

    const int len = klen[b];
    const float q0 = s_q[c4], q1 = s_q[c4 + 1], q2 = s_q[c4 + 2], q3 = s_q[c4 + 3];

    // ---- phase 1: scores. wave-half h covers row 2p+h; p strided by 4 waves.
    // unroll x2: two independent 1KB wave-loads + interleaved 5-step half-wave reductions
    {
        int p = wid;
        for (; p + 4 < TT / 2; p += 8) {
            const int r0 = 2 * p + h;
            const int r1 = r0 + 8;
            const float4 k0 = *(const float4*)(kb + r0 * CC + c4);
            const float4 k1 = *(const float4*)(kb + r1 * CC + c4);
            float d0 = q0 * k0.x + q1 * k0.y + q2 * k0.z + q3 * k0.w;
            float d1 = q0 * k1.x + q1 * k1.y + q2 * k1.z + q3 * k1.w;
            #pragma unroll
            for (int off = 1; off < 32; off <<= 1) {
                d0 += __shfl_xor(d0, off, 64);
                d1 += __shfl_xor(d1, off, 64);
            }
            if (cl == 0) {
                s_w[r0] = (r0 < len) ? d0 * SCALE : PADV;
                s_w[r1] = (r1 < len) ? d1 * SCALE : PADV;
            }
        }
        if (p < TT / 2) {                 // tail (p = wid + 96)
            const int r0 = 2 * p + h;
            const float4 k0 = *(const float4*)(kb + r0 * CC + c4);
            float d0 = q0 * k0.x + q1 * k0.y + q2 * k0.z + q3 * k0.w;
            #pragma unroll
            for (int off = 1; off < 32; off <<= 1)
                d0 += __shfl_xor(d0, off, 64);
            if (cl == 0)
                s_w[r0] = (r0 < len) ? d0 * SCALE : PADV;
        }
    }
    __syncthreads();

    // ---- phase 2: softmax -> coeff[t] = softmax[t] + 1/T  (all-PAD => uniform 1/T)
    {
        float v = (tid < TT) ? s_w[tid] : -INFINITY;
        float m = v;
        #pragma unroll
        for (int off = 1; off < 64; off <<= 1)
            m = fmaxf(m, __shfl_xor(m, off, 64));
        if (lane == 0) s_tmp[wid] = m;
        __syncthreads();
        m = fmaxf(fmaxf(s_tmp[0], s_tmp[1]), fmaxf(s_tmp[2], s_tmp[3]));

        float e = (tid < TT) ? expf(v - m) : 0.0f;
        float ssum = e;
        #pragma unroll
        for (int off = 1; off < 64; off <<= 1)
            ssum += __shfl_xor(ssum, off, 64);
        if (lane == 0) s_tmp[4 + wid] = ssum;
        __syncthreads();
        ssum = (s_tmp[4] + s_tmp[5]) + (s_tmp[6] + s_tmp[7]);
        if (tid < TT) s_w[tid] = e / ssum + INVT;
    }
    __syncthreads();

    // ---- phase 3: out[c] = sum_t coeff[t]*keys[t,c]; second global pass (L2/L3 hit)
    float4 acc = make_float4(0.0f, 0.0f, 0.0f, 0.0f);
    #pragma unroll 2
    for (int p = wid; p < TT / 2; p += 4) {
        const int r = 2 * p + h;
        const float w  = s_w[r];
        const float4 k = *(const float4*)(kb + r * CC + c4);
        acc.x = fmaf(w, k.x, acc.x);
        acc.y = fmaf(w, k.y, acc.y);
        acc.z = fmaf(w, k.z, acc.z);
        acc.w = fmaf(w, k.w, acc.w);
    }
    // combine two halves (same channels, disjoint rows)
    acc.x += __shfl_xor(acc.x, 32, 64);
    acc.y += __shfl_xor(acc.y, 32, 64);
    acc.z += __shfl_xor(acc.z, 32, 64);
    acc.w += __shfl_xor(acc.w, 32, 64);

    if (h == 0) s_red[wid * 32 + cl] = acc;
    __syncthreads();

    if (tid < 32) {
        float4 r0 = s_red[tid];
        const float4 r1 = s_red[32 + tid];
        const float4 r2 = s_red[64 + tid];
        const float4 r3 = s_red[96 + tid];
        r0.x += (r1.x + r2.x) + r3.x;
        r0.y += (r1.y + r2.y) + r3.y;
        r0.z += (r1.z + r2.z) + r3.z;
        r0.w += (r1.w + r2.w) + r3.w;
        *(float4*)(out + (size_t)b * CC + 4 * tid) = r0;
    }
}

extern "C" void kernel_launch(void* const* d_in, const int* in_sizes, int n_in,
                              void* d_out, int out_size, void* d_ws, size_t ws_size,
                              hipStream_t stream) {
    const float* uq   = (const float*)d_in[0];
    const float* keys = (const float*)d_in[1];
    const int*   klen = (const int*)d_in[2];
    const float* W    = (const float*)d_in[3];
    const float* bias = (const float*)d_in[4];
    float* out = (float*)d_out;

    user_attn_kernel<<<BB, 256, 0, stream>>>(uq, keys, klen, W, bias, out);
}

// Round 4
// 302.961 us; speedup vs baseline: 1.0540x; 1.0540x over previous
//
#include <hip/hip_runtime.h>
#include <math.h>

#define BB 2048
#define TT 200
#define CC 128
#define PADV (-4294967295.0f)
#define SCALE 0.08838834764831845f   // 1/sqrt(128)
#define INVT (1.0f / 200.0f)
#define PITCH 132                    // bf16/row in LDS: 264 B -> 2-way bank alias only (free)

__device__ __forceinline__ float bf2f(unsigned short u) {
    return __uint_as_float((unsigned)u << 16);
}

// ---- kernel 1: q[b][d] = tanh(bias[d] + sum_c uq[b][c] * W[c][d]) for all b
// 1024 blocks x 256 thr; each thread one (b,d). W rows L2-hot after first touch.
__global__ __launch_bounds__(256) void q_gemv_kernel(
    const float* __restrict__ uq,   // [B,C]
    const float* __restrict__ W,    // [C,C]
    const float* __restrict__ bias, // [C]
    float*       __restrict__ qws)  // [B,C] (d_ws)
{
    const int tid = threadIdx.x;
    const int d   = tid & 127;
    const int wh  = tid >> 7;                 // 0/1: which of 2 batch rows
    const int b   = blockIdx.x * 2 + wh;

    __shared__ float s_uq[2 * CC];
    s_uq[tid] = uq[blockIdx.x * 2 * CC + tid];
    __syncthreads();

    float acc = bias[d];
    const float* uqr = &s_uq[wh * CC];
    #pragma unroll 16
    for (int c = 0; c < CC; ++c)
        acc = fmaf(uqr[c], W[c * CC + d], acc);
    qws[(size_t)b * CC + d] = tanhf(acc);
}

// ---- kernel 2: one block per batch row; 512 thr; single global pass over keys.
// LDS: 52800 (bf16 keys) + 512 + 800 + 64 = 54176 B -> 3 blocks/CU (163840/3 = 54613).
__global__ __launch_bounds__(512, 6) void attn_main_kernel(
    const float* __restrict__ keys, // [B,T,C]
    const int*   __restrict__ klen, // [B,1]
    const float* __restrict__ qws,  // [B,C] precomputed query
    float*       __restrict__ out)  // [B,1,C]
{
    const int b    = blockIdx.x;
    const int tid  = threadIdx.x;
    const int lane = tid & 63;
    const int wid  = tid >> 6;       // 0..7

    __shared__ unsigned short s_k[TT * PITCH]; // 52800 B
    __shared__ float s_q[CC];
    __shared__ float s_w[TT];
    __shared__ float s_tmp[16];
    float4* s_red = (float4*)s_k;    // alias, used only after all s_k reads complete

    const float*  kb = keys + (size_t)b * TT * CC;
    const float4* gp = (const float4*)kb + tid;      // chunk idx = tid + 512*i

    if (tid < CC) s_q[tid] = qws[(size_t)b * CC + tid];
    const int len = klen[b];

    // ---- phase A: stage keys -> LDS bf16. 6400 float4-chunks; chunk = (row, ch-quad).
    // row = chunk>>5, quad = chunk&31. Per-thread rows r0+16i, fixed quad.
    {
        const int r0 = tid >> 5;         // 0..15
        const int cq = tid & 31;         // channel quad
        const int l0 = r0 * PITCH + cq * 4;   // ushort index; +i*16*PITCH per step
        #pragma unroll 4
        for (int i = 0; i < 12; ++i) {
            const float4 k = gp[512 * i];
            ushort4 pk;
            pk.x = (unsigned short)(__float_as_uint(k.x) >> 16);
            pk.y = (unsigned short)(__float_as_uint(k.y) >> 16);
            pk.z = (unsigned short)(__float_as_uint(k.z) >> 16);
            pk.w = (unsigned short)(__float_as_uint(k.w) >> 16);
            *(ushort4*)&s_k[l0 + i * 16 * PITCH] = pk;
        }
        if (tid < 256) {                 // tail: rows 192..199
            const float4 k = gp[512 * 12];
            ushort4 pk;
            pk.x = (unsigned short)(__float_as_uint(k.x) >> 16);
            pk.y = (unsigned short)(__float_as_uint(k.y) >> 16);
            pk.z = (unsigned short)(__float_as_uint(k.z) >> 16);
            pk.w = (unsigned short)(__float_as_uint(k.w) >> 16);
            *(ushort4*)&s_k[l0 + 12 * 16 * PITCH] = pk;
        }
    }
    __syncthreads();

    // ---- phase B: scores, NO shuffles: thread t dots its own LDS row vs broadcast s_q
    if (tid < TT) {
        const ushort4* rowp = (const ushort4*)&s_k[tid * PITCH];
        float a0 = 0.f, a1 = 0.f, a2 = 0.f, a3 = 0.f;
        #pragma unroll 8
        for (int j = 0; j < 32; ++j) {
            const ushort4 pk = rowp[j];
            const float* qj = &s_q[4 * j];
            a0 = fmaf(qj[0], bf2f(pk.x), a0);
            a1 = fmaf(qj[1], bf2f(pk.y), a1);
            a2 = fmaf(qj[2], bf2f(pk.z), a2);
            a3 = fmaf(qj[3], bf2f(pk.w), a3);
        }
        const float d = (a0 + a1) + (a2 + a3);
        s_w[tid] = (tid < len) ? d * SCALE : PADV;
    }
    __syncthreads();

    // ---- phase C: softmax -> coeff[t] = softmax[t] + 1/T (all-PAD => uniform 1/T)
    {
        float v = (tid < TT) ? s_w[tid] : -INFINITY;
        float m = v;
        #pragma unroll
        for (int off = 1; off < 64; off <<= 1)
            m = fmaxf(m, __shfl_xor(m, off, 64));
        if (lane == 0) s_tmp[wid] = m;
        __syncthreads();
        m = s_tmp[0];
        #pragma unroll
        for (int w = 1; w < 8; ++w) m = fmaxf(m, s_tmp[w]);

        float e = (tid < TT) ? expf(v - m) : 0.0f;
        float ssum = e;
        #pragma unroll
        for (int off = 1; off < 64; off <<= 1)
            ssum += __shfl_xor(ssum, off, 64);
        if (lane == 0) s_tmp[8 + wid] = ssum;
        __syncthreads();
        ssum = 0.0f;
        #pragma unroll
        for (int w = 0; w < 8; ++w) ssum += s_tmp[8 + w];
        if (tid < TT) s_w[tid] = e / ssum + INVT;
    }
    __syncthreads();

    // ---- phase D: out[c] = sum_t coeff[t] * k_bf16[t][c], from LDS
    const int cl = lane & 31;        // channel quad
    const int h  = lane >> 5;        // row parity within pair
    float4 acc = make_float4(0.f, 0.f, 0.f, 0.f);
    for (int p = wid; p < TT / 2; p += 8) {
        const int r = 2 * p + h;
        const float w = s_w[r];
        const ushort4 pk = *(const ushort4*)&s_k[r * PITCH + cl * 4];
        acc.x = fmaf(w, bf2f(pk.x), acc.x);
        acc.y = fmaf(w, bf2f(pk.y), acc.y);
        acc.z = fmaf(w, bf2f(pk.z), acc.z);
        acc.w = fmaf(w, bf2f(pk.w), acc.w);
    }
    acc.x += __shfl_xor(acc.x, 32, 64);
    acc.y += __shfl_xor(acc.y, 32, 64);
    acc.z += __shfl_xor(acc.z, 32, 64);
    acc.w += __shfl_xor(acc.w, 32, 64);

    __syncthreads();                 // s_k reads done; safe to alias as s_red
    if (h == 0) s_red[wid * 32 + cl] = acc;
    __syncthreads();

    if (tid < 32) {
        float4 r = s_red[tid];
        #pragma unroll
        for (int w = 1; w < 8; ++w) {
            const float4 v = s_red[w * 32 + tid];
            r.x += v.x; r.y += v.y; r.z += v.z; r.w += v.w;
        }
        *(float4*)(out + (size_t)b * CC + 4 * tid) = r;
    }
}

extern "C" void kernel_launch(void* const* d_in, const int* in_sizes, int n_in,
                              void* d_out, int out_size, void* d_ws, size_t ws_size,
                              hipStream_t stream) {
    const float* uq   = (const float*)d_in[0];
    const float* keys = (const float*)d_in[1];
    const int*   klen = (const int*)d_in[2];
    const float* W    = (const float*)d_in[3];
    const float* bias = (const float*)d_in[4];
    float* out = (float*)d_out;
    float* qws = (float*)d_ws;       // 2048*128*4 = 1 MB scratch

    q_gemv_kernel<<<BB / 2, 256, 0, stream>>>(uq, W, bias, qws);
    attn_main_kernel<<<BB, 512, 0, stream>>>(keys, klen, qws, out);
}

// Round 5
// 300.593 us; speedup vs baseline: 1.0623x; 1.0079x over previous
//
#include <hip/hip_runtime.h>
#include <math.h>

#define BB 2048
#define TT 200
#define CC 128
#define PADV (-4294967295.0f)
#define SCALE 0.08838834764831845f   // 1/sqrt(128)
#define INV_T (1.0f / 200.0f)

// ---- kernel 1: q[b][d] = tanh(bias[d] + sum_c uq[b][c] * W[c][d]) for all b
__global__ __launch_bounds__(256) void q_gemv_kernel(
    const float* __restrict__ uq,   // [B,C]
    const float* __restrict__ W,    // [C,C]
    const float* __restrict__ bias, // [C]
    float*       __restrict__ qws)  // [B,C] (d_ws)
{
    const int tid = threadIdx.x;
    const int d   = tid & 127;
    const int wh  = tid >> 7;                 // 0/1: which of 2 batch rows
    const int b   = blockIdx.x * 2 + wh;

    __shared__ float s_uq[2 * CC];
    s_uq[tid] = uq[blockIdx.x * 2 * CC + tid];
    __syncthreads();

    float acc = bias[d];
    const float* uqr = &s_uq[wh * CC];
    #pragma unroll 16
    for (int c = 0; c < CC; ++c)
        acc = fmaf(uqr[c], W[c * CC + d], acc);
    qws[(size_t)b * CC + d] = tanhf(acc);
}

// ---- kernel 2: one block per batch row; 256 thr = 4 waves = 8 half-waves.
// SINGLE streaming pass over keys with per-half online softmax; no key staging.
// Half g owns rows {g, g+8, ..., g+192} (25 rows); lanes of a wave cover a
// contiguous 1 KB (rows 2w and 2w+1) per load. LDS ~8.3 KB.
__global__ __launch_bounds__(256, 6) void attn_stream_kernel(
    const float* __restrict__ keys, // [B,T,C]
    const int*   __restrict__ klen, // [B,1]
    const float* __restrict__ qws,  // [B,C] precomputed query
    float*       __restrict__ out)  // [B,1,C]
{
    const int b    = blockIdx.x;
    const int tid  = threadIdx.x;
    const int lane = tid & 63;
    const int wid  = tid >> 6;       // 0..3
    const int cl   = lane & 31;      // channel-quad lane
    const int h    = lane >> 5;      // half-wave
    const int g    = wid * 2 + h;    // half index 0..7
    const int c4   = cl * 4;

    __shared__ float  s_m[8];
    __shared__ float  s_l[8];
    __shared__ float4 s_acc[8 * 32];
    __shared__ float4 s_ksum[8 * 32];

    const float* kb  = keys + (size_t)b * TT * CC;
    const int    len = klen[b];
    const float4 q   = *(const float4*)(qws + (size_t)b * CC + c4);

    float  m = -INFINITY, l = 0.0f;
    float4 acc  = make_float4(0.f, 0.f, 0.f, 0.f);
    float4 ksum = make_float4(0.f, 0.f, 0.f, 0.f);

    // online update; masked rows get PADV and flow through the same recurrence:
    //  - mixed row: exp(PADV - m_real) underflows to 0 (no contribution)
    //  - all-PAD:   exp(0) = 1 everywhere -> uniform weights, matching jax
    auto upd = [&](float d, const float4& k, int r) {
        const float s  = (r < len) ? d * SCALE : PADV;
        const float mn = fmaxf(m, s);
        const float sc = __expf(m - mn);      // exp(-inf)=0 on first row
        const float p  = __expf(s - mn);
        l = fmaf(l, sc, p);
        acc.x = fmaf(p, k.x, acc.x * sc);
        acc.y = fmaf(p, k.y, acc.y * sc);
        acc.z = fmaf(p, k.z, acc.z * sc);
        acc.w = fmaf(p, k.w, acc.w * sc);
        ksum.x += k.x; ksum.y += k.y; ksum.z += k.z; ksum.w += k.w;
        m = mn;
    };

    for (int outer = 0; outer < 5; ++outer) {
        const int r0 = g + 40 * outer;        // rows r0 + {0,8,16,24,32}
        const float4 k0 = *(const float4*)(kb + (r0     ) * CC + c4);
        const float4 k1 = *(const float4*)(kb + (r0 +  8) * CC + c4);
        const float4 k2 = *(const float4*)(kb + (r0 + 16) * CC + c4);
        const float4 k3 = *(const float4*)(kb + (r0 + 24) * CC + c4);
        const float4 k4 = *(const float4*)(kb + (r0 + 32) * CC + c4);

        float d0 = q.x * k0.x + q.y * k0.y + q.z * k0.z + q.w * k0.w;
        float d1 = q.x * k1.x + q.y * k1.y + q.z * k1.z + q.w * k1.w;
        float d2 = q.x * k2.x + q.y * k2.y + q.z * k2.z + q.w * k2.w;
        float d3 = q.x * k3.x + q.y * k3.y + q.z * k3.z + q.w * k3.w;
        float d4 = q.x * k4.x + q.y * k4.y + q.z * k4.z + q.w * k4.w;

        #pragma unroll
        for (int off = 1; off < 32; off <<= 1) {   // butterfly within 32-lane half
            d0 += __shfl_xor(d0, off, 64);
            d1 += __shfl_xor(d1, off, 64);
            d2 += __shfl_xor(d2, off, 64);
            d3 += __shfl_xor(d3, off, 64);
            d4 += __shfl_xor(d4, off, 64);
        }

        upd(d0, k0, r0);
        upd(d1, k1, r0 + 8);
        upd(d2, k2, r0 + 16);
        upd(d3, k3, r0 + 24);
        upd(d4, k4, r0 + 32);
    }

    // ---- merge 8 half-wave states
    s_acc [g * 32 + cl] = acc;
    s_ksum[g * 32 + cl] = ksum;
    if (cl == 0) { s_m[g] = m; s_l[g] = l; }
    __syncthreads();

    if (tid < 32) {
        float M = s_m[0];
        #pragma unroll
        for (int i = 1; i < 8; ++i) M = fmaxf(M, s_m[i]);

        float  L  = 0.0f;
        float4 A  = make_float4(0.f, 0.f, 0.f, 0.f);
        float4 KS = make_float4(0.f, 0.f, 0.f, 0.f);
        #pragma unroll
        for (int i = 0; i < 8; ++i) {
            const float al = __expf(s_m[i] - M);   // kills padded-only halves
            L = fmaf(s_l[i], al, L);
            const float4 a = s_acc[i * 32 + tid];
            A.x = fmaf(a.x, al, A.x);
            A.y = fmaf(a.y, al, A.y);
            A.z = fmaf(a.z, al, A.z);
            A.w = fmaf(a.w, al, A.w);
            const float4 ks = s_ksum[i * 32 + tid];
            KS.x += ks.x; KS.y += ks.y; KS.z += ks.z; KS.w += ks.w;
        }
        const float invL = 1.0f / L;               // L >= 1 (max half has p=1 row)
        float4 o;
        o.x = fmaf(A.x, invL, KS.x * INV_T);
        o.y = fmaf(A.y, invL, KS.y * INV_T);
        o.z = fmaf(A.z, invL, KS.z * INV_T);
        o.w = fmaf(A.w, invL, KS.w * INV_T);
        *(float4*)(out + (size_t)b * CC + 4 * tid) = o;
    }
}

extern "C" void kernel_launch(void* const* d_in, const int* in_sizes, int n_in,
                              void* d_out, int out_size, void* d_ws, size_t ws_size,
                              hipStream_t stream) {
    const float* uq   = (const float*)d_in[0];
    const float* keys = (const float*)d_in[1];
    const int*   klen = (const int*)d_in[2];
    const float* W    = (const float*)d_in[3];
    const float* bias = (const float*)d_in[4];
    float* out = (float*)d_out;
    float* qws = (float*)d_ws;       // 2048*128*4 = 1 MB scratch

    q_gemv_kernel<<<BB / 2, 256, 0, stream>>>(uq, W, bias, qws);
    attn_stream_kernel<<<BB, 256, 0, stream>>>(keys, klen, qws, out);
}

// Round 6
// 299.824 us; speedup vs baseline: 1.0650x; 1.0026x over previous
//
#include <hip/hip_runtime.h>
#include <math.h>

#define BB 2048
#define TT 200
#define CC 128
#define PADV (-4294967295.0f)
#define SCALE 0.08838834764831845f   // 1/sqrt(128)
#define INV_T (1.0f / 200.0f)

// Single fused kernel: one block per batch row, 256 thr = 4 waves = 8 half-waves.
// Phase 0: q = tanh(uq@W+b) block-GEMV (W coalesced, L2-hot).
// Phase 1: ONE streaming pass over keys; per-half online softmax, 5-row batched
//          update (single rescale/group) + software prefetch of the next group.
// out[c] = attn/L + ksum/T  (residual+mean folded).
__global__ __launch_bounds__(256, 4) void user_attn_fused(
    const float* __restrict__ uq,    // [B,C]
    const float* __restrict__ keys,  // [B,T,C]
    const int*   __restrict__ klen,  // [B,1]
    const float* __restrict__ W,     // [C,C]
    const float* __restrict__ bias,  // [C]
    float*       __restrict__ out)   // [B,C]
{
    const int b    = blockIdx.x;
    const int tid  = threadIdx.x;
    const int lane = tid & 63;
    const int wid  = tid >> 6;       // 0..3
    const int cl   = lane & 31;      // channel-quad lane
    const int h    = lane >> 5;      // half-wave
    const int g    = wid * 2 + h;    // half index 0..7
    const int c4   = cl * 4;

    __shared__ float  s_uq[CC];
    __shared__ float  s_part[2 * CC];
    __shared__ float  s_q[CC];
    __shared__ float  s_m[8];
    __shared__ float  s_l[8];
    __shared__ float4 s_acc[8 * 32];
    __shared__ float4 s_ksum[8 * 32];

    // ---- phase 0: q = tanh(uq @ W + bias)
    if (tid < CC) s_uq[tid] = uq[(size_t)b * CC + tid];
    __syncthreads();
    {
        const int d    = tid & 127;
        const int part = tid >> 7;       // 0/1
        const int c0   = part * 64;
        float a = 0.0f;
        #pragma unroll 16
        for (int c = 0; c < 64; ++c)
            a = fmaf(s_uq[c0 + c], W[(c0 + c) * CC + d], a);
        s_part[part * CC + d] = a;
    }
    __syncthreads();
    if (tid < CC) s_q[tid] = tanhf(bias[tid] + s_part[tid] + s_part[CC + tid]);
    __syncthreads();

    const int    len = klen[b];
    const float4 q   = *(const float4*)&s_q[c4];
    // float4 index for (row r, quad cl) = r*32 + cl; half g starts at row g
    const float4* kp = (const float4*)(keys + (size_t)b * TT * CC) + g * 32 + cl;

    float  m = -INFINITY, l = 0.0f;
    float4 acc  = make_float4(0.f, 0.f, 0.f, 0.f);
    float4 ksum = make_float4(0.f, 0.f, 0.f, 0.f);

    // group j covers rows g + 40j + {0,8,16,24,32}; float4 offsets 1280j + 256i
    float4 c0_ = kp[0], c1_ = kp[256], c2_ = kp[512], c3_ = kp[768], c4_ = kp[1024];

    #pragma unroll
    for (int j = 0; j < 5; ++j) {
        float4 n0, n1, n2, n3, n4;
        if (j < 4) {                     // prefetch next group while computing this one
            const float4* np = kp + 1280 * (j + 1);
            n0 = np[0]; n1 = np[256]; n2 = np[512]; n3 = np[768]; n4 = np[1024];
        }

        float d0 = q.x * c0_.x + q.y * c0_.y + q.z * c0_.z + q.w * c0_.w;
        float d1 = q.x * c1_.x + q.y * c1_.y + q.z * c1_.z + q.w * c1_.w;
        float d2 = q.x * c2_.x + q.y * c2_.y + q.z * c2_.z + q.w * c2_.w;
        float d3 = q.x * c3_.x + q.y * c3_.y + q.z * c3_.z + q.w * c3_.w;
        float d4 = q.x * c4_.x + q.y * c4_.y + q.z * c4_.z + q.w * c4_.w;

        #pragma unroll
        for (int off = 1; off < 32; off <<= 1) {   // butterfly within 32-lane half
            d0 += __shfl_xor(d0, off, 64);
            d1 += __shfl_xor(d1, off, 64);
            d2 += __shfl_xor(d2, off, 64);
            d3 += __shfl_xor(d3, off, 64);
            d4 += __shfl_xor(d4, off, 64);
        }

        const int r0 = g + 40 * j;
        const float s0 = (r0      < len) ? d0 * SCALE : PADV;
        const float s1 = (r0 +  8 < len) ? d1 * SCALE : PADV;
        const float s2 = (r0 + 16 < len) ? d2 * SCALE : PADV;
        const float s3 = (r0 + 24 < len) ? d3 * SCALE : PADV;
        const float s4 = (r0 + 32 < len) ? d4 * SCALE : PADV;

        // batched online-softmax update: ONE rescale per 5 rows
        const float gm = fmaxf(fmaxf(fmaxf(s0, s1), fmaxf(s2, s3)), s4);
        const float mn = fmaxf(m, gm);             // finite (gm >= PADV)
        const float sc = __expf(m - mn);           // first group: exp(-inf)=0
        const float p0 = __expf(s0 - mn);
        const float p1 = __expf(s1 - mn);
        const float p2 = __expf(s2 - mn);
        const float p3 = __expf(s3 - mn);
        const float p4 = __expf(s4 - mn);
        l = fmaf(l, sc, ((p0 + p1) + (p2 + p3)) + p4);
        acc.x = fmaf(p0, c0_.x, fmaf(p1, c1_.x, fmaf(p2, c2_.x, fmaf(p3, c3_.x, fmaf(p4, c4_.x, acc.x * sc)))));
        acc.y = fmaf(p0, c0_.y, fmaf(p1, c1_.y, fmaf(p2, c2_.y, fmaf(p3, c3_.y, fmaf(p4, c4_.y, acc.y * sc)))));
        acc.z = fmaf(p0, c0_.z, fmaf(p1, c1_.z, fmaf(p2, c2_.z, fmaf(p3, c3_.z, fmaf(p4, c4_.z, acc.z * sc)))));
        acc.w = fmaf(p0, c0_.w, fmaf(p1, c1_.w, fmaf(p2, c2_.w, fmaf(p3, c3_.w, fmaf(p4, c4_.w, acc.w * sc)))));
        ksum.x += ((c0_.x + c1_.x) + (c2_.x + c3_.x)) + c4_.x;
        ksum.y += ((c0_.y + c1_.y) + (c2_.y + c3_.y)) + c4_.y;
        ksum.z += ((c0_.z + c1_.z) + (c2_.z + c3_.z)) + c4_.z;
        ksum.w += ((c0_.w + c1_.w) + (c2_.w + c3_.w)) + c4_.w;
        m = mn;

        c0_ = n0; c1_ = n1; c2_ = n2; c3_ = n3; c4_ = n4;
    }

    // ---- merge 8 half-wave states
    s_acc [g * 32 + cl] = acc;
    s_ksum[g * 32 + cl] = ksum;
    if (cl == 0) { s_m[g] = m; s_l[g] = l; }
    __syncthreads();

    if (tid < 32) {
        float M = s_m[0];
        #pragma unroll
        for (int i = 1; i < 8; ++i) M = fmaxf(M, s_m[i]);

        float  L  = 0.0f;
        float4 A  = make_float4(0.f, 0.f, 0.f, 0.f);
        float4 KS = make_float4(0.f, 0.f, 0.f, 0.f);
        #pragma unroll
        for (int i = 0; i < 8; ++i) {
            const float al = __expf(s_m[i] - M);
            L = fmaf(s_l[i], al, L);
            const float4 a = s_acc[i * 32 + tid];
            A.x = fmaf(a.x, al, A.x);
            A.y = fmaf(a.y, al, A.y);
            A.z = fmaf(a.z, al, A.z);
            A.w = fmaf(a.w, al, A.w);
            const float4 ks = s_ksum[i * 32 + tid];
            KS.x += ks.x; KS.y += ks.y; KS.z += ks.z; KS.w += ks.w;
        }
        const float invL = 1.0f / L;   // L >= 1 always
        float4 o;
        o.x = fmaf(A.x, invL, KS.x * INV_T);
        o.y = fmaf(A.y, invL, KS.y * INV_T);
        o.z = fmaf(A.z, invL, KS.z * INV_T);
        o.w = fmaf(A.w, invL, KS.w * INV_T);
        *(float4*)(out + (size_t)b * CC + 4 * tid) = o;
    }
}

extern "C" void kernel_launch(void* const* d_in, const int* in_sizes, int n_in,
                              void* d_out, int out_size, void* d_ws, size_t ws_size,
                              hipStream_t stream) {
    const float* uq   = (const float*)d_in[0];
    const float* keys = (const float*)d_in[1];
    const int*   klen = (const int*)d_in[2];
    const float* W    = (const float*)d_in[3];
    const float* bias = (const float*)d_in[4];
    float* out = (float*)d_out;

    user_attn_fused<<<BB, 256, 0, stream>>>(uq, keys, klen, W, bias, out);
}

// Round 7
// 297.290 us; speedup vs baseline: 1.0741x; 1.0085x over previous
//
#include <hip/hip_runtime.h>
#include <math.h>

#define BB 2048
#define TT 200
#define CC 128
#define PADV (-4294967295.0f)
#define SCALE 0.08838834764831845f   // 1/sqrt(128)
#define INV_T (1.0f / 200.0f)

// Single fused kernel: one block per batch row, 256 thr = 4 waves = 8 half-waves.
// Group-0 keys loads are hoisted ABOVE the q-GEMV so HBM stays busy during the
// (chip-wide simultaneous) prologue. Then one streaming pass with per-half
// online softmax, batched 5-row updates, depth-1 prefetch.
__global__ __launch_bounds__(256, 4) void user_attn_fused(
    const float* __restrict__ uq,    // [B,C]
    const float* __restrict__ keys,  // [B,T,C]
    const int*   __restrict__ klen,  // [B,1]
    const float* __restrict__ W,     // [C,C]
    const float* __restrict__ bias,  // [C]
    float*       __restrict__ out)   // [B,C]
{
    const int b    = blockIdx.x;
    const int tid  = threadIdx.x;
    const int lane = tid & 63;
    const int wid  = tid >> 6;       // 0..3
    const int cl   = lane & 31;      // channel-quad lane
    const int h    = lane >> 5;      // half-wave
    const int g    = wid * 2 + h;    // half index 0..7
    const int c4   = cl * 4;

    __shared__ float  s_uq[CC];
    __shared__ float  s_part[2 * CC];
    __shared__ float  s_q[CC];
    __shared__ float  s_m[8];
    __shared__ float  s_l[8];
    __shared__ float4 s_acc[8 * 32];
    __shared__ float4 s_ksum[8 * 32];

    // float4 index for (row r, quad cl) = r*32 + cl; half g owns rows g+8k
    const float4* kp = (const float4*)(keys + (size_t)b * TT * CC) + g * 32 + cl;

    // ---- hoisted group-0 prefetch: issues BEFORE the GEMV so the memory
    // system streams keys while every block runs its prologue
    float4 c0_ = kp[0], c1_ = kp[256], c2_ = kp[512], c3_ = kp[768], c4_ = kp[1024];
    const int len = klen[b];

    // ---- phase 0: q = tanh(uq @ W + bias)
    if (tid < CC) s_uq[tid] = uq[(size_t)b * CC + tid];
    __syncthreads();
    {
        const int d    = tid & 127;
        const int part = tid >> 7;       // 0/1
        const int c0   = part * 64;
        float a = 0.0f;
        #pragma unroll 16
        for (int c = 0; c < 64; ++c)
            a = fmaf(s_uq[c0 + c], W[(c0 + c) * CC + d], a);
        s_part[part * CC + d] = a;
    }
    __syncthreads();
    if (tid < CC) s_q[tid] = tanhf(bias[tid] + s_part[tid] + s_part[CC + tid]);
    __syncthreads();

    const float4 q = *(const float4*)&s_q[c4];

    float  m = -INFINITY, l = 0.0f;
    float4 acc  = make_float4(0.f, 0.f, 0.f, 0.f);
    float4 ksum = make_float4(0.f, 0.f, 0.f, 0.f);

    #pragma unroll
    for (int j = 0; j < 5; ++j) {
        float4 n0, n1, n2, n3, n4;
        if (j < 4) {                     // prefetch next group while computing this one
            const float4* np = kp + 1280 * (j + 1);
            n0 = np[0]; n1 = np[256]; n2 = np[512]; n3 = np[768]; n4 = np[1024];
        }

        float d0 = q.x * c0_.x + q.y * c0_.y + q.z * c0_.z + q.w * c0_.w;
        float d1 = q.x * c1_.x + q.y * c1_.y + q.z * c1_.z + q.w * c1_.w;
        float d2 = q.x * c2_.x + q.y * c2_.y + q.z * c2_.z + q.w * c2_.w;
        float d3 = q.x * c3_.x + q.y * c3_.y + q.z * c3_.z + q.w * c3_.w;
        float d4 = q.x * c4_.x + q.y * c4_.y + q.z * c4_.z + q.w * c4_.w;

        #pragma unroll
        for (int off = 1; off < 32; off <<= 1) {   // butterfly within 32-lane half
            d0 += __shfl_xor(d0, off, 64);
            d1 += __shfl_xor(d1, off, 64);
            d2 += __shfl_xor(d2, off, 64);
            d3 += __shfl_xor(d3, off, 64);
            d4 += __shfl_xor(d4, off, 64);
        }

        const int r0 = g + 40 * j;
        const float s0 = (r0      < len) ? d0 * SCALE : PADV;
        const float s1 = (r0 +  8 < len) ? d1 * SCALE : PADV;
        const float s2 = (r0 + 16 < len) ? d2 * SCALE : PADV;
        const float s3 = (r0 + 24 < len) ? d3 * SCALE : PADV;
        const float s4 = (r0 + 32 < len) ? d4 * SCALE : PADV;

        // batched online-softmax update: ONE rescale per 5 rows
        const float gm = fmaxf(fmaxf(fmaxf(s0, s1), fmaxf(s2, s3)), s4);
        const float mn = fmaxf(m, gm);             // finite (gm >= PADV)
        const float sc = __expf(m - mn);           // first group: exp(-inf)=0
        const float p0 = __expf(s0 - mn);
        const float p1 = __expf(s1 - mn);
        const float p2 = __expf(s2 - mn);
        const float p3 = __expf(s3 - mn);
        const float p4 = __expf(s4 - mn);
        l = fmaf(l, sc, ((p0 + p1) + (p2 + p3)) + p4);
        acc.x = fmaf(p0, c0_.x, fmaf(p1, c1_.x, fmaf(p2, c2_.x, fmaf(p3, c3_.x, fmaf(p4, c4_.x, acc.x * sc)))));
        acc.y = fmaf(p0, c0_.y, fmaf(p1, c1_.y, fmaf(p2, c2_.y, fmaf(p3, c3_.y, fmaf(p4, c4_.y, acc.y * sc)))));
        acc.z = fmaf(p0, c0_.z, fmaf(p1, c1_.z, fmaf(p2, c2_.z, fmaf(p3, c3_.z, fmaf(p4, c4_.z, acc.z * sc)))));
        acc.w = fmaf(p0, c0_.w, fmaf(p1, c1_.w, fmaf(p2, c2_.w, fmaf(p3, c3_.w, fmaf(p4, c4_.w, acc.w * sc)))));
        ksum.x += ((c0_.x + c1_.x) + (c2_.x + c3_.x)) + c4_.x;
        ksum.y += ((c0_.y + c1_.y) + (c2_.y + c3_.y)) + c4_.y;
        ksum.z += ((c0_.z + c1_.z) + (c2_.z + c3_.z)) + c4_.z;
        ksum.w += ((c0_.w + c1_.w) + (c2_.w + c3_.w)) + c4_.w;
        m = mn;

        c0_ = n0; c1_ = n1; c2_ = n2; c3_ = n3; c4_ = n4;
    }

    // ---- merge 8 half-wave states
    s_acc [g * 32 + cl] = acc;
    s_ksum[g * 32 + cl] = ksum;
    if (cl == 0) { s_m[g] = m; s_l[g] = l; }
    __syncthreads();

    if (tid < 32) {
        float M = s_m[0];
        #pragma unroll
        for (int i = 1; i < 8; ++i) M = fmaxf(M, s_m[i]);

        float  L  = 0.0f;
        float4 A  = make_float4(0.f, 0.f, 0.f, 0.f);
        float4 KS = make_float4(0.f, 0.f, 0.f, 0.f);
        #pragma unroll
        for (int i = 0; i < 8; ++i) {
            const float al = __expf(s_m[i] - M);
            L = fmaf(s_l[i], al, L);
            const float4 a = s_acc[i * 32 + tid];
            A.x = fmaf(a.x, al, A.x);
            A.y = fmaf(a.y, al, A.y);
            A.z = fmaf(a.z, al, A.z);
            A.w = fmaf(a.w, al, A.w);
            const float4 ks = s_ksum[i * 32 + tid];
            KS.x += ks.x; KS.y += ks.y; KS.z += ks.z; KS.w += ks.w;
        }
        const float invL = 1.0f / L;   // L >= 1 always
        float4 o;
        o.x = fmaf(A.x, invL, KS.x * INV_T);
        o.y = fmaf(A.y, invL, KS.y * INV_T);
        o.z = fmaf(A.z, invL, KS.z * INV_T);
        o.w = fmaf(A.w, invL, KS.w * INV_T);
        *(float4*)(out + (size_t)b * CC + 4 * tid) = o;
    }
}

extern "C" void kernel_launch(void* const* d_in, const int* in_sizes, int n_in,
                              void* d_out, int out_size, void* d_ws, size_t ws_size,
                              hipStream_t stream) {
    const float* uq   = (const float*)d_in[0];
    const float* keys = (const float*)d_in[1];
    const int*   klen = (const int*)d_in[2];
    const float* W    = (const float*)d_in[3];
    const float* bias = (const float*)d_in[4];
    float* out = (float*)d_out;

    user_attn_fused<<<BB, 256, 0, stream>>>(uq, keys, klen, W, bias, out);
}